// Round 1
// baseline (360.035 us; speedup 1.0000x reference)
//
#include <hip/hip_runtime.h>
#include <hip/hip_bf16.h>

#define S_LEN 4096
#define BATCH 4
#define DMODEL 1024
#define HDIM 128

typedef __attribute__((ext_vector_type(8))) short short8;
typedef __attribute__((ext_vector_type(4))) short short4v;
typedef __attribute__((ext_vector_type(4))) float float4v;

static __device__ __forceinline__ unsigned short f2bf(float f) {
    __hip_bfloat16 h = __float2bfloat16(f);
    return *reinterpret_cast<unsigned short*>(&h);
}

// ---------------------------------------------------------------------------
// Kernel A: QKV projection.  out = x @ W^T  (M=16384, K=1024, N=128)
// x: (S,B,D) fp32 -> row m = s*B+b is linear.  W: (H,D) fp32 (B^T layout).
// Output: (B,S,H) bf16.  Scale folded into Q.
// ---------------------------------------------------------------------------
__global__ __launch_bounds__(256) void qkv_proj_kernel(
    const float* __restrict__ x, const float* __restrict__ Wq,
    const float* __restrict__ Wk, const float* __restrict__ Wv,
    unsigned short* __restrict__ Qb, unsigned short* __restrict__ Kb,
    unsigned short* __restrict__ Vb)
{
    __shared__ unsigned short As[128 * 72];   // 128 rows x 64 k, stride 72 (pad)
    __shared__ unsigned short Bs[128 * 72];

    const int t = threadIdx.x;
    const int m0 = blockIdx.x * 128;
    const int which = blockIdx.y;            // 0=Q 1=K 2=V
    const float* W = (which == 0) ? Wq : (which == 1) ? Wk : Wv;
    unsigned short* Out = (which == 0) ? Qb : (which == 1) ? Kb : Vb;

    const int lane = t & 63;
    const int w = t >> 6;
    const int wr = (w >> 1) * 64;
    const int wc = (w & 1) * 64;
    const int l15 = lane & 15;
    const int l4 = lane >> 4;

    float4v acc[4][4];
#pragma unroll
    for (int i = 0; i < 4; i++)
#pragma unroll
        for (int j = 0; j < 4; j++) acc[i][j] = (float4v){0.f, 0.f, 0.f, 0.f};

    const int krow = t >> 4;        // 0..15 (row within a 16-row pass)
    const int kcol4 = (t & 15) * 4; // float4 column within 64-wide k-step

    for (int k0 = 0; k0 < DMODEL; k0 += 64) {
        __syncthreads();
        // stage x tile (128 x 64) fp32 -> bf16
#pragma unroll
        for (int p = 0; p < 8; p++) {
            int row = p * 16 + krow;
            float4 v = *reinterpret_cast<const float4*>(
                &x[(size_t)(m0 + row) * DMODEL + k0 + kcol4]);
            short4v h;
            h[0] = (short)f2bf(v.x); h[1] = (short)f2bf(v.y);
            h[2] = (short)f2bf(v.z); h[3] = (short)f2bf(v.w);
            *reinterpret_cast<short4v*>(&As[row * 72 + kcol4]) = h;
        }
        // stage W tile (128 x 64) fp32 -> bf16
#pragma unroll
        for (int p = 0; p < 8; p++) {
            int row = p * 16 + krow;
            float4 v = *reinterpret_cast<const float4*>(
                &W[(size_t)row * DMODEL + k0 + kcol4]);
            short4v h;
            h[0] = (short)f2bf(v.x); h[1] = (short)f2bf(v.y);
            h[2] = (short)f2bf(v.z); h[3] = (short)f2bf(v.w);
            *reinterpret_cast<short4v*>(&Bs[row * 72 + kcol4]) = h;
        }
        __syncthreads();

#pragma unroll
        for (int kk = 0; kk < 64; kk += 32) {
            short8 a[4], b[4];
#pragma unroll
            for (int mi = 0; mi < 4; mi++)
                a[mi] = *reinterpret_cast<const short8*>(
                    &As[(wr + mi * 16 + l15) * 72 + kk + l4 * 8]);
#pragma unroll
            for (int ni = 0; ni < 4; ni++)
                b[ni] = *reinterpret_cast<const short8*>(
                    &Bs[(wc + ni * 16 + l15) * 72 + kk + l4 * 8]);
#pragma unroll
            for (int mi = 0; mi < 4; mi++)
#pragma unroll
                for (int ni = 0; ni < 4; ni++)
                    acc[mi][ni] = __builtin_amdgcn_mfma_f32_16x16x32_bf16(
                        a[mi], b[ni], acc[mi][ni], 0, 0, 0);
        }
    }

    const float scale = (which == 0) ? 0.08838834764831845f : 1.0f;
#pragma unroll
    for (int mi = 0; mi < 4; mi++)
#pragma unroll
        for (int ni = 0; ni < 4; ni++)
#pragma unroll
            for (int r = 0; r < 4; r++) {
                int m = m0 + wr + mi * 16 + l4 * 4 + r;
                int h = wc + ni * 16 + l15;
                float v = acc[mi][ni][r] * scale;
                int b = m & 3, s = m >> 2;
                Out[((size_t)b * S_LEN + s) * HDIM + h] = f2bf(v);
            }
}

// ---------------------------------------------------------------------------
// Kernel B: causal flash attention.  Q,K,V: (B,S,H) bf16.  O: (B,S,H) bf16.
// Block = 4 waves = 64 q rows (16 per wave).  KV blocks of 64.
// ---------------------------------------------------------------------------
__global__ __launch_bounds__(256) void attn_kernel(
    const unsigned short* __restrict__ Qb, const unsigned short* __restrict__ Kb,
    const unsigned short* __restrict__ Vb, unsigned short* __restrict__ Ob)
{
    __shared__ unsigned short Ks[64 * 128];   // swizzled rows
    __shared__ unsigned short Vt[128 * 64];   // transposed, swizzled rows
    __shared__ unsigned short Pl[4 * 16 * 64];

    const int t = threadIdx.x;
    const int w = t >> 6;
    const int lane = t & 63;
    const int l15 = lane & 15, l4 = lane >> 4;
    const int qtile = blockIdx.x;
    const int b = blockIdx.y;
    const int qb = qtile * 64;
    const size_t base = (size_t)b * S_LEN * HDIM;

    // Q fragments (16 rows per wave), held in registers
    short8 qf[4];
    {
        int qrow = qb + w * 16 + l15;
#pragma unroll
        for (int kk = 0; kk < 4; kk++)
            qf[kk] = *reinterpret_cast<const short8*>(
                &Qb[base + (size_t)qrow * HDIM + kk * 32 + l4 * 8]);
    }

    float m_run[4], l_run[4];
    float4v acc_o[8];
#pragma unroll
    for (int r = 0; r < 4; r++) { m_run[r] = -INFINITY; l_run[r] = 0.f; }
#pragma unroll
    for (int hf = 0; hf < 8; hf++) acc_o[hf] = (float4v){0.f, 0.f, 0.f, 0.f};

    const int nt = qtile + 1;
    for (int ti = 0; ti < nt; ti++) {
        int kvb = ti * 64;
        __syncthreads();
        // stage K 64x128 (row-swizzled ^((r&7)<<4))
#pragma unroll
        for (int p = 0; p < 4; p++) {
            int e = p * 2048 + t * 8;
            int r = e >> 7, h = e & 127;
            uint4 v = *reinterpret_cast<const uint4*>(
                &Kb[base + (size_t)(kvb + r) * HDIM + h]);
            int byteoff = (r * 256 + h * 2) ^ ((r & 7) << 4);
            *reinterpret_cast<uint4*>(reinterpret_cast<char*>(Ks) + byteoff) = v;
        }
        // stage V transposed: Vt[h][kv] (row h swizzled ^((h&7)<<4))
#pragma unroll
        for (int p = 0; p < 4; p++) {
            int e = p * 2048 + t * 8;
            int r = e >> 7, h0 = e & 127;
            short8 v = *reinterpret_cast<const short8*>(
                &Vb[base + (size_t)(kvb + r) * HDIM + h0]);
#pragma unroll
            for (int j = 0; j < 8; j++) {
                int h = h0 + j;
                int byteoff = (h * 128 + r * 2) ^ ((h & 7) << 4);
                *reinterpret_cast<short*>(reinterpret_cast<char*>(Vt) + byteoff) = v[j];
            }
        }
        __syncthreads();

        // S = Q K^T  (4 col-fragments of 16 kv)
        float4v accs[4];
#pragma unroll
        for (int f = 0; f < 4; f++) {
            accs[f] = (float4v){0.f, 0.f, 0.f, 0.f};
#pragma unroll
            for (int kk = 0; kk < 4; kk++) {
                int krow = f * 16 + l15;
                int byteoff = (krow * 256 + (kk * 32 + l4 * 8) * 2) ^ ((krow & 7) << 4);
                short8 kf = *reinterpret_cast<const short8*>(
                    reinterpret_cast<const char*>(Ks) + byteoff);
                accs[f] = __builtin_amdgcn_mfma_f32_16x16x32_bf16(qf[kk], kf, accs[f], 0, 0, 0);
            }
        }
        // causal mask (diagonal block only)
        if (ti == qtile) {
#pragma unroll
            for (int f = 0; f < 4; f++)
#pragma unroll
                for (int r = 0; r < 4; r++) {
                    int q = qb + w * 16 + l4 * 4 + r;
                    int kv = kvb + f * 16 + l15;
                    if (kv > q) accs[f][r] = -1e30f;
                }
        }
        // online softmax (per q-row; rows live in 16-lane groups, reg r)
        float alpha[4];
#pragma unroll
        for (int r = 0; r < 4; r++) {
            float mx = accs[0][r];
#pragma unroll
            for (int f = 1; f < 4; f++) mx = fmaxf(mx, accs[f][r]);
#pragma unroll
            for (int d = 1; d < 16; d <<= 1) mx = fmaxf(mx, __shfl_xor(mx, d));
            float mnew = fmaxf(m_run[r], mx);
            alpha[r] = __expf(m_run[r] - mnew);
            m_run[r] = mnew;
        }
        float p[4][4];
#pragma unroll
        for (int f = 0; f < 4; f++)
#pragma unroll
            for (int r = 0; r < 4; r++)
                p[f][r] = __expf(accs[f][r] - m_run[r]);
#pragma unroll
        for (int r = 0; r < 4; r++) {
            float s = 0.f;
#pragma unroll
            for (int f = 0; f < 4; f++) s += p[f][r];
#pragma unroll
            for (int d = 1; d < 16; d <<= 1) s += __shfl_xor(s, d);
            l_run[r] = l_run[r] * alpha[r] + s;
#pragma unroll
            for (int hf = 0; hf < 8; hf++) acc_o[hf][r] *= alpha[r];
        }
        // P -> per-wave LDS (bf16, row-swizzled), then read as A-fragments
        char* pbase = reinterpret_cast<char*>(Pl) + w * 2048;
#pragma unroll
        for (int f = 0; f < 4; f++)
#pragma unroll
            for (int r = 0; r < 4; r++) {
                int row = l4 * 4 + r;
                int kv = f * 16 + l15;
                int byteoff = (row * 128 + kv * 2) ^ ((row & 7) << 4);
                *reinterpret_cast<short*>(pbase + byteoff) = (short)f2bf(p[f][r]);
            }
        // PV: O += P @ V
#pragma unroll
        for (int kk = 0; kk < 2; kk++) {
            int prow = l15;
            int pkv = kk * 32 + l4 * 8;
            int pboff = (prow * 128 + pkv * 2) ^ ((prow & 7) << 4);
            short8 pa = *reinterpret_cast<const short8*>(pbase + pboff);
#pragma unroll
            for (int hf = 0; hf < 8; hf++) {
                int h = hf * 16 + l15;
                int vboff = (h * 128 + pkv * 2) ^ ((h & 7) << 4);
                short8 vf = *reinterpret_cast<const short8*>(
                    reinterpret_cast<const char*>(Vt) + vboff);
                acc_o[hf] = __builtin_amdgcn_mfma_f32_16x16x32_bf16(pa, vf, acc_o[hf], 0, 0, 0);
            }
        }
    }

    // epilogue: O = acc / l
#pragma unroll
    for (int hf = 0; hf < 8; hf++)
#pragma unroll
        for (int r = 0; r < 4; r++) {
            int q = qb + w * 16 + l4 * 4 + r;
            int h = hf * 16 + l15;
            float v = acc_o[hf][r] / l_run[r];
            Ob[base + (size_t)q * HDIM + h] = f2bf(v);
        }
}

// ---------------------------------------------------------------------------
// Kernel C: output projection. out[(s*B+b)*D + d] = sum_h O[b][s][h]*Wo[d][h]
// M=16384, K=128 (single pass), N=1024.  Output fp32.
// ---------------------------------------------------------------------------
__global__ __launch_bounds__(256) void out_proj_kernel(
    const unsigned short* __restrict__ Ob, const float* __restrict__ Wo,
    float* __restrict__ out)
{
    __shared__ unsigned short As[128 * 128];
    __shared__ unsigned short Bs[128 * 128];

    const int t = threadIdx.x;
    const int lane = t & 63, w = t >> 6;
    const int l15 = lane & 15, l4 = lane >> 4;
    const int wr = (w >> 1) * 64, wc = (w & 1) * 64;
    const int m0 = blockIdx.x * 128;
    const int d0 = blockIdx.y * 128;

    // stage A: O rows (scattered b,s), swizzled
#pragma unroll
    for (int p = 0; p < 8; p++) {
        int e = p * 2048 + t * 8;
        int r = e >> 7, h = e & 127;
        int m = m0 + r;
        uint4 v = *reinterpret_cast<const uint4*>(
            &Ob[((size_t)(m & 3) * S_LEN + (m >> 2)) * HDIM + h]);
        int byteoff = (r * 256 + h * 2) ^ ((r & 7) << 4);
        *reinterpret_cast<uint4*>(reinterpret_cast<char*>(As) + byteoff) = v;
    }
    // stage B: Wo tile fp32 -> bf16, swizzled
#pragma unroll
    for (int p = 0; p < 16; p++) {
        int e = p * 1024 + t * 4;
        int r = e >> 7, h = e & 127;
        float4 v = *reinterpret_cast<const float4*>(&Wo[(size_t)(d0 + r) * HDIM + h]);
        short4v hh;
        hh[0] = (short)f2bf(v.x); hh[1] = (short)f2bf(v.y);
        hh[2] = (short)f2bf(v.z); hh[3] = (short)f2bf(v.w);
        int byteoff = (r * 256 + h * 2) ^ ((r & 7) << 4);
        *reinterpret_cast<short4v*>(reinterpret_cast<char*>(Bs) + byteoff) = hh;
    }
    __syncthreads();

    float4v acc[4][4];
#pragma unroll
    for (int i = 0; i < 4; i++)
#pragma unroll
        for (int j = 0; j < 4; j++) acc[i][j] = (float4v){0.f, 0.f, 0.f, 0.f};

#pragma unroll
    for (int kk = 0; kk < 4; kk++) {
        short8 a[4], bf[4];
#pragma unroll
        for (int mi = 0; mi < 4; mi++) {
            int row = wr + mi * 16 + l15;
            int off = (row * 256 + (kk * 32 + l4 * 8) * 2) ^ ((row & 7) << 4);
            a[mi] = *reinterpret_cast<const short8*>(reinterpret_cast<const char*>(As) + off);
        }
#pragma unroll
        for (int ni = 0; ni < 4; ni++) {
            int row = wc + ni * 16 + l15;
            int off = (row * 256 + (kk * 32 + l4 * 8) * 2) ^ ((row & 7) << 4);
            bf[ni] = *reinterpret_cast<const short8*>(reinterpret_cast<const char*>(Bs) + off);
        }
#pragma unroll
        for (int mi = 0; mi < 4; mi++)
#pragma unroll
            for (int ni = 0; ni < 4; ni++)
                acc[mi][ni] = __builtin_amdgcn_mfma_f32_16x16x32_bf16(
                    a[mi], bf[ni], acc[mi][ni], 0, 0, 0);
    }

#pragma unroll
    for (int mi = 0; mi < 4; mi++)
#pragma unroll
        for (int ni = 0; ni < 4; ni++)
#pragma unroll
            for (int r = 0; r < 4; r++) {
                int m = m0 + wr + mi * 16 + l4 * 4 + r;
                int d = d0 + wc + ni * 16 + l15;
                out[(size_t)m * DMODEL + d] = acc[mi][ni][r];
            }
}

// ---------------------------------------------------------------------------
extern "C" void kernel_launch(void* const* d_in, const int* in_sizes, int n_in,
                              void* d_out, int out_size, void* d_ws, size_t ws_size,
                              hipStream_t stream) {
    const float* x  = (const float*)d_in[0];
    const float* Wq = (const float*)d_in[1];
    const float* Wk = (const float*)d_in[2];
    const float* Wv = (const float*)d_in[3];
    const float* Wo = (const float*)d_in[4];
    float* out = (float*)d_out;

    const size_t elems = (size_t)BATCH * S_LEN * HDIM; // 2M bf16 = 4MB
    unsigned short* Qb = (unsigned short*)d_ws;
    unsigned short* Kb = Qb + elems;
    unsigned short* Vb = Kb + elems;
    unsigned short* Ob = Vb + elems;

    qkv_proj_kernel<<<dim3(128, 3), 256, 0, stream>>>(x, Wq, Wk, Wv, Qb, Kb, Vb);
    attn_kernel<<<dim3(64, 4), 256, 0, stream>>>(Qb, Kb, Vb, Ob);
    out_proj_kernel<<<dim3(128, 8), 256, 0, stream>>>(Ob, Wo, out);
}

// Round 2
// 251.366 us; speedup vs baseline: 1.4323x; 1.4323x over previous
//
#include <hip/hip_runtime.h>
#include <hip/hip_bf16.h>

#define S_LEN 4096
#define BATCH 4
#define DMODEL 1024
#define HDIM 128
#define NSLOT 4   // max KV chunks per q-tile (chunk = 16 kv-blocks = 1024 kv)

typedef __attribute__((ext_vector_type(8))) short short8;
typedef __attribute__((ext_vector_type(4))) short short4v;
typedef __attribute__((ext_vector_type(4))) float float4v;

static __device__ __forceinline__ unsigned short f2bf(float f) {
    __hip_bfloat16 h = __float2bfloat16(f);
    return *reinterpret_cast<unsigned short*>(&h);
}
static __device__ __forceinline__ unsigned short f2h(float f) {
    _Float16 h = (_Float16)f; return *reinterpret_cast<unsigned short*>(&h);
}
static __device__ __forceinline__ float h2f(unsigned short u) {
    _Float16 h = *reinterpret_cast<_Float16*>(&u); return (float)h;
}

// ---------------------------------------------------------------------------
// Kernel A: QKV projection, per-batch tiled.  For which=0/1 writes (B,S,H);
// for which=2 (V) swaps MFMA operands and writes V^T as (B,H,S).
// ---------------------------------------------------------------------------
__global__ __launch_bounds__(256) void qkv_proj_kernel(
    const float* __restrict__ x, const float* __restrict__ Wq,
    const float* __restrict__ Wk, const float* __restrict__ Wv,
    unsigned short* __restrict__ Qb, unsigned short* __restrict__ Kb,
    unsigned short* __restrict__ Vtb)
{
    __shared__ unsigned short As[128 * 72];
    __shared__ unsigned short Bs[128 * 72];

    const int t = threadIdx.x;
    const int s0 = blockIdx.x * 128;
    const int b = blockIdx.y;
    const int which = blockIdx.z;
    const float* W = (which == 0) ? Wq : (which == 1) ? Wk : Wv;

    const int lane = t & 63;
    const int w = t >> 6;
    const int wr = (w >> 1) * 64;
    const int wc = (w & 1) * 64;
    const int l15 = lane & 15;
    const int l4 = lane >> 4;

    float4v acc[4][4];
#pragma unroll
    for (int i = 0; i < 4; i++)
#pragma unroll
        for (int j = 0; j < 4; j++) acc[i][j] = (float4v){0.f, 0.f, 0.f, 0.f};

    const int krow = t >> 4;
    const int kcol4 = (t & 15) * 4;

    for (int k0 = 0; k0 < DMODEL; k0 += 64) {
        __syncthreads();
#pragma unroll
        for (int p = 0; p < 8; p++) {
            int row = p * 16 + krow;
            float4 v = *reinterpret_cast<const float4*>(
                &x[((size_t)(s0 + row) * BATCH + b) * DMODEL + k0 + kcol4]);
            short4v h;
            h[0] = (short)f2bf(v.x); h[1] = (short)f2bf(v.y);
            h[2] = (short)f2bf(v.z); h[3] = (short)f2bf(v.w);
            *reinterpret_cast<short4v*>(&As[row * 72 + kcol4]) = h;
        }
#pragma unroll
        for (int p = 0; p < 8; p++) {
            int row = p * 16 + krow;
            float4 v = *reinterpret_cast<const float4*>(
                &W[(size_t)row * DMODEL + k0 + kcol4]);
            short4v h;
            h[0] = (short)f2bf(v.x); h[1] = (short)f2bf(v.y);
            h[2] = (short)f2bf(v.z); h[3] = (short)f2bf(v.w);
            *reinterpret_cast<short4v*>(&Bs[row * 72 + kcol4]) = h;
        }
        __syncthreads();

#pragma unroll
        for (int kk = 0; kk < 64; kk += 32) {
            short8 a[4], bfr[4];
#pragma unroll
            for (int mi = 0; mi < 4; mi++)
                a[mi] = *reinterpret_cast<const short8*>(
                    &As[(wr + mi * 16 + l15) * 72 + kk + l4 * 8]);
#pragma unroll
            for (int ni = 0; ni < 4; ni++)
                bfr[ni] = *reinterpret_cast<const short8*>(
                    &Bs[(wc + ni * 16 + l15) * 72 + kk + l4 * 8]);
            if (which != 2) {
#pragma unroll
                for (int mi = 0; mi < 4; mi++)
#pragma unroll
                    for (int ni = 0; ni < 4; ni++)
                        acc[mi][ni] = __builtin_amdgcn_mfma_f32_16x16x32_bf16(
                            a[mi], bfr[ni], acc[mi][ni], 0, 0, 0);
            } else {
#pragma unroll
                for (int mi = 0; mi < 4; mi++)
#pragma unroll
                    for (int ni = 0; ni < 4; ni++)
                        acc[mi][ni] = __builtin_amdgcn_mfma_f32_16x16x32_bf16(
                            bfr[ni], a[mi], acc[mi][ni], 0, 0, 0);
            }
        }
    }

    if (which != 2) {
        unsigned short* Out = (which == 0) ? Qb : Kb;
        const float scale = (which == 0) ? 0.08838834764831845f : 1.0f;
#pragma unroll
        for (int mi = 0; mi < 4; mi++)
#pragma unroll
            for (int ni = 0; ni < 4; ni++)
#pragma unroll
                for (int r = 0; r < 4; r++) {
                    int s = s0 + wr + mi * 16 + l4 * 4 + r;
                    int h = wc + ni * 16 + l15;
                    Out[((size_t)b * S_LEN + s) * HDIM + h] =
                        f2bf(acc[mi][ni][r] * scale);
                }
    } else {
        // acc[mi][ni]: rows = W rows (h), cols = x rows (s)
#pragma unroll
        for (int mi = 0; mi < 4; mi++)
#pragma unroll
            for (int ni = 0; ni < 4; ni++)
#pragma unroll
                for (int r = 0; r < 4; r++) {
                    int h = wc + ni * 16 + l4 * 4 + r;
                    int s = s0 + wr + mi * 16 + l15;
                    Vtb[((size_t)b * HDIM + h) * S_LEN + s] = f2bf(acc[mi][ni][r]);
                }
    }
}

// ---------------------------------------------------------------------------
// Kernel B: causal flash attention, KV-chunked.
// Block = 4 waves = 64 q rows (16/wave).  Each block: one (b, qtile, chunk).
// Writes normalized fp16 partial O + per-row (m, l) for its chunk slot.
// ---------------------------------------------------------------------------
__global__ __launch_bounds__(256) void attn_kernel(
    const unsigned short* __restrict__ Qb, const unsigned short* __restrict__ Kb,
    const unsigned short* __restrict__ Vtb, unsigned short* __restrict__ Opart,
    float* __restrict__ Mpart, float* __restrict__ Lpart)
{
    __shared__ unsigned short Ks[64 * 128];   // [kv][h], row-swizzled
    __shared__ unsigned short Vs[128 * 64];   // [h][kv], row-swizzled
    __shared__ unsigned short Pl[4 * 16 * 64];

    const int t = threadIdx.x;
    const int w = t >> 6;
    const int lane = t & 63;
    const int l15 = lane & 15, l4 = lane >> 4;
    const int b = blockIdx.y;

    // flat block index -> (qtile, chunk); cnt(qtile)=ceil((qtile+1)/16)
    int f = blockIdx.x, qtile, c;
    if (f < 16)      { qtile = f;                    c = 0; }
    else if (f < 48) { qtile = 16 + ((f - 16) >> 1); c = (f - 16) & 1; }
    else if (f < 96) { qtile = 32 + (f - 48) / 3;    c = (f - 48) % 3; }
    else             { qtile = 48 + ((f - 96) >> 2); c = (f - 96) & 3; }

    const int lo = c * 16;
    const int hi = min(lo + 16, qtile + 1);
    const int qb = qtile * 64;
    const size_t base = (size_t)b * S_LEN * HDIM;

    // Q fragments (16 rows per wave)
    short8 qf[4];
    {
        int qrow = qb + w * 16 + l15;
#pragma unroll
        for (int kk = 0; kk < 4; kk++)
            qf[kk] = *reinterpret_cast<const short8*>(
                &Qb[base + (size_t)qrow * HDIM + kk * 32 + l4 * 8]);
    }

    float m_run[4], l_run[4];
    float4v acc_o[8];
#pragma unroll
    for (int r = 0; r < 4; r++) { m_run[r] = -INFINITY; l_run[r] = 0.f; }
#pragma unroll
    for (int hf = 0; hf < 8; hf++) acc_o[hf] = (float4v){0.f, 0.f, 0.f, 0.f};

    // staging assignments
    const int kr = t >> 2, kc = (t & 3) * 32;   // K: row kv, 4 thr/row
    const int vh = t >> 1, vc = (t & 1) * 32;   // V^T: row h, 2 thr/row
    uint4 kreg[4], vreg[4];
    {
        int kvb = lo * 64;
        const unsigned short* kp = &Kb[base + (size_t)(kvb + kr) * HDIM + kc];
#pragma unroll
        for (int j = 0; j < 4; j++)
            kreg[j] = *reinterpret_cast<const uint4*>(kp + j * 8);
        const unsigned short* vp = &Vtb[((size_t)b * HDIM + vh) * S_LEN + kvb + vc];
#pragma unroll
        for (int j = 0; j < 4; j++)
            vreg[j] = *reinterpret_cast<const uint4*>(vp + j * 8);
    }

    for (int ti = lo; ti < hi; ti++) {
        int kvb = ti * 64;
        __syncthreads();   // previous iteration's LDS reads done
#pragma unroll
        for (int j = 0; j < 4; j++) {
            int off = (kr * 256 + (kc + j * 8) * 2) ^ ((kr & 7) << 4);
            *reinterpret_cast<uint4*>(reinterpret_cast<char*>(Ks) + off) = kreg[j];
        }
#pragma unroll
        for (int j = 0; j < 4; j++) {
            int off = (vh * 128 + (vc + j * 8) * 2) ^ ((vh & 7) << 4);
            *reinterpret_cast<uint4*>(reinterpret_cast<char*>(Vs) + off) = vreg[j];
        }
        __syncthreads();
        if (ti + 1 < hi) {   // prefetch next tile into regs; hides under MFMA
            int kvb2 = (ti + 1) * 64;
            const unsigned short* kp = &Kb[base + (size_t)(kvb2 + kr) * HDIM + kc];
#pragma unroll
            for (int j = 0; j < 4; j++)
                kreg[j] = *reinterpret_cast<const uint4*>(kp + j * 8);
            const unsigned short* vp = &Vtb[((size_t)b * HDIM + vh) * S_LEN + kvb2 + vc];
#pragma unroll
            for (int j = 0; j < 4; j++)
                vreg[j] = *reinterpret_cast<const uint4*>(vp + j * 8);
        }

        // S = Q K^T
        float4v accs[4];
#pragma unroll
        for (int fi = 0; fi < 4; fi++) {
            accs[fi] = (float4v){0.f, 0.f, 0.f, 0.f};
#pragma unroll
            for (int kk = 0; kk < 4; kk++) {
                int krow = fi * 16 + l15;
                int off = (krow * 256 + (kk * 32 + l4 * 8) * 2) ^ ((krow & 7) << 4);
                short8 kf = *reinterpret_cast<const short8*>(
                    reinterpret_cast<const char*>(Ks) + off);
                accs[fi] = __builtin_amdgcn_mfma_f32_16x16x32_bf16(
                    qf[kk], kf, accs[fi], 0, 0, 0);
            }
        }
        if (ti == qtile) {   // diagonal block: causal mask
#pragma unroll
            for (int fi = 0; fi < 4; fi++)
#pragma unroll
                for (int r = 0; r < 4; r++) {
                    int q = qb + w * 16 + l4 * 4 + r;
                    int kv = kvb + fi * 16 + l15;
                    if (kv > q) accs[fi][r] = -1e30f;
                }
        }
        // online softmax (rows live in 16-lane groups)
        float alpha[4];
#pragma unroll
        for (int r = 0; r < 4; r++) {
            float mx = fmaxf(fmaxf(accs[0][r], accs[1][r]),
                             fmaxf(accs[2][r], accs[3][r]));
#pragma unroll
            for (int d = 1; d < 16; d <<= 1) mx = fmaxf(mx, __shfl_xor(mx, d));
            float mnew = fmaxf(m_run[r], mx);
            alpha[r] = __expf(m_run[r] - mnew);
            m_run[r] = mnew;
        }
        float p[4][4];
#pragma unroll
        for (int fi = 0; fi < 4; fi++)
#pragma unroll
            for (int r = 0; r < 4; r++)
                p[fi][r] = __expf(accs[fi][r] - m_run[r]);
#pragma unroll
        for (int r = 0; r < 4; r++) {
            float s = p[0][r] + p[1][r] + p[2][r] + p[3][r];
#pragma unroll
            for (int d = 1; d < 16; d <<= 1) s += __shfl_xor(s, d);
            l_run[r] = l_run[r] * alpha[r] + s;
#pragma unroll
            for (int hf = 0; hf < 8; hf++) acc_o[hf][r] *= alpha[r];
        }
        // P -> per-wave LDS
        char* pbase = reinterpret_cast<char*>(Pl) + w * 2048;
#pragma unroll
        for (int fi = 0; fi < 4; fi++)
#pragma unroll
            for (int r = 0; r < 4; r++) {
                int row = l4 * 4 + r;
                int kv = fi * 16 + l15;
                int off = (row * 128 + kv * 2) ^ ((row & 7) << 4);
                *reinterpret_cast<short*>(pbase + off) = (short)f2bf(p[fi][r]);
            }
        // O += P @ V
#pragma unroll
        for (int kk = 0; kk < 2; kk++) {
            int poff = (l15 * 128 + (kk * 32 + l4 * 8) * 2) ^ ((l15 & 7) << 4);
            short8 pa = *reinterpret_cast<const short8*>(pbase + poff);
#pragma unroll
            for (int hf = 0; hf < 8; hf++) {
                int h = hf * 16 + l15;
                int voff = (h * 128 + (kk * 32 + l4 * 8) * 2) ^ ((h & 7) << 4);
                short8 vf = *reinterpret_cast<const short8*>(
                    reinterpret_cast<const char*>(Vs) + voff);
                acc_o[hf] = __builtin_amdgcn_mfma_f32_16x16x32_bf16(
                    pa, vf, acc_o[hf], 0, 0, 0);
            }
        }
    }

    // epilogue: normalized fp16 partial + (m,l)
    const size_t R0 = (size_t)(c * BATCH + b) * S_LEN;
#pragma unroll
    for (int r = 0; r < 4; r++) {
        int q = qb + w * 16 + l4 * 4 + r;
        float inv = 1.f / l_run[r];
#pragma unroll
        for (int hf = 0; hf < 8; hf++) {
            int h = hf * 16 + l15;
            Opart[(R0 + q) * HDIM + h] = f2h(acc_o[hf][r] * inv);
        }
        if (l15 == 0) { Mpart[R0 + q] = m_run[r]; Lpart[R0 + q] = l_run[r]; }
    }
}

// ---------------------------------------------------------------------------
// Kernel B2: combine partials -> Ob (B,S,H) bf16
// ---------------------------------------------------------------------------
__global__ __launch_bounds__(256) void combine_kernel(
    const unsigned short* __restrict__ Opart, const float* __restrict__ Mpart,
    const float* __restrict__ Lpart, unsigned short* __restrict__ Ob)
{
    const int BS = BATCH * S_LEN;
    int idx = blockIdx.x * 256 + threadIdx.x;
    int r = idx >> 4, hc = (idx & 15) * 8;
    int q = r & (S_LEN - 1);
    int cnt = ((q >> 6) + 16) >> 4;   // ceil((qtile+1)/16)

    float m = -INFINITY;
    for (int j = 0; j < cnt; j++) m = fmaxf(m, Mpart[j * BS + r]);
    float wsum = 0.f;
    float acc[8];
#pragma unroll
    for (int e = 0; e < 8; e++) acc[e] = 0.f;
    for (int j = 0; j < cnt; j++) {
        float wj = __expf(Mpart[j * BS + r] - m) * Lpart[j * BS + r];
        wsum += wj;
        short8 o = *reinterpret_cast<const short8*>(
            &Opart[((size_t)j * BS + r) * HDIM + hc]);
#pragma unroll
        for (int e = 0; e < 8; e++) acc[e] += wj * h2f((unsigned short)o[e]);
    }
    float inv = 1.f / wsum;
    short8 ob;
#pragma unroll
    for (int e = 0; e < 8; e++) ob[e] = (short)f2bf(acc[e] * inv);
    *reinterpret_cast<short8*>(&Ob[(size_t)r * HDIM + hc]) = ob;
}

// ---------------------------------------------------------------------------
// Kernel C: output projection, per-batch tiled.
// out[(s*B+b)*D + d] = sum_h Ob[b][s][h] * Wo[d][h]
// ---------------------------------------------------------------------------
__global__ __launch_bounds__(256) void out_proj_kernel(
    const unsigned short* __restrict__ Ob, const float* __restrict__ Wo,
    float* __restrict__ out)
{
    __shared__ unsigned short As[128 * 128];
    __shared__ unsigned short Bs[128 * 128];

    const int t = threadIdx.x;
    const int lane = t & 63, w = t >> 6;
    const int l15 = lane & 15, l4 = lane >> 4;
    const int wr = (w >> 1) * 64, wc = (w & 1) * 64;
    const int s0 = blockIdx.x * 128;
    const int d0 = blockIdx.y * 128;
    const int b = blockIdx.z;

#pragma unroll
    for (int p = 0; p < 8; p++) {
        int e = p * 2048 + t * 8;
        int r = e >> 7, h = e & 127;
        short8 v = *reinterpret_cast<const short8*>(
            &Ob[((size_t)b * S_LEN + s0 + r) * HDIM + h]);
        int off = (r * 256 + h * 2) ^ ((r & 7) << 4);
        *reinterpret_cast<short8*>(reinterpret_cast<char*>(As) + off) = v;
    }
#pragma unroll
    for (int p = 0; p < 16; p++) {
        int e = p * 1024 + t * 4;
        int r = e >> 7, h = e & 127;
        float4 v = *reinterpret_cast<const float4*>(&Wo[(size_t)(d0 + r) * HDIM + h]);
        short4v hh;
        hh[0] = (short)f2bf(v.x); hh[1] = (short)f2bf(v.y);
        hh[2] = (short)f2bf(v.z); hh[3] = (short)f2bf(v.w);
        int off = (r * 256 + h * 2) ^ ((r & 7) << 4);
        *reinterpret_cast<short4v*>(reinterpret_cast<char*>(Bs) + off) = hh;
    }
    __syncthreads();

    float4v acc[4][4];
#pragma unroll
    for (int i = 0; i < 4; i++)
#pragma unroll
        for (int j = 0; j < 4; j++) acc[i][j] = (float4v){0.f, 0.f, 0.f, 0.f};

#pragma unroll
    for (int kk = 0; kk < 4; kk++) {
        short8 a[4], bf[4];
#pragma unroll
        for (int mi = 0; mi < 4; mi++) {
            int row = wr + mi * 16 + l15;
            int off = (row * 256 + (kk * 32 + l4 * 8) * 2) ^ ((row & 7) << 4);
            a[mi] = *reinterpret_cast<const short8*>(
                reinterpret_cast<const char*>(As) + off);
        }
#pragma unroll
        for (int ni = 0; ni < 4; ni++) {
            int row = wc + ni * 16 + l15;
            int off = (row * 256 + (kk * 32 + l4 * 8) * 2) ^ ((row & 7) << 4);
            bf[ni] = *reinterpret_cast<const short8*>(
                reinterpret_cast<const char*>(Bs) + off);
        }
#pragma unroll
        for (int mi = 0; mi < 4; mi++)
#pragma unroll
            for (int ni = 0; ni < 4; ni++)
                acc[mi][ni] = __builtin_amdgcn_mfma_f32_16x16x32_bf16(
                    a[mi], bf[ni], acc[mi][ni], 0, 0, 0);
    }

#pragma unroll
    for (int mi = 0; mi < 4; mi++)
#pragma unroll
        for (int ni = 0; ni < 4; ni++)
#pragma unroll
            for (int r = 0; r < 4; r++) {
                int s = s0 + wr + mi * 16 + l4 * 4 + r;
                int d = d0 + wc + ni * 16 + l15;
                out[((size_t)s * BATCH + b) * DMODEL + d] = acc[mi][ni][r];
            }
}

// ---------------------------------------------------------------------------
extern "C" void kernel_launch(void* const* d_in, const int* in_sizes, int n_in,
                              void* d_out, int out_size, void* d_ws, size_t ws_size,
                              hipStream_t stream) {
    const float* x  = (const float*)d_in[0];
    const float* Wq = (const float*)d_in[1];
    const float* Wk = (const float*)d_in[2];
    const float* Wv = (const float*)d_in[3];
    const float* Wo = (const float*)d_in[4];
    float* out = (float*)d_out;

    const size_t elems = (size_t)BATCH * S_LEN * HDIM;     // 2M
    const size_t BS = (size_t)BATCH * S_LEN;               // 16384
    unsigned short* Qb    = (unsigned short*)d_ws;
    unsigned short* Kb    = Qb + elems;
    unsigned short* Vtb   = Kb + elems;
    unsigned short* Ob    = Vtb + elems;
    unsigned short* Opart = Ob + elems;                    // NSLOT*BS*H fp16
    float* Mpart = (float*)(Opart + (size_t)NSLOT * BS * HDIM);
    float* Lpart = Mpart + (size_t)NSLOT * BS;

    qkv_proj_kernel<<<dim3(32, BATCH, 3), 256, 0, stream>>>(x, Wq, Wk, Wv, Qb, Kb, Vtb);
    attn_kernel<<<dim3(160, BATCH), 256, 0, stream>>>(Qb, Kb, Vtb, Opart, Mpart, Lpart);
    combine_kernel<<<dim3(1024), 256, 0, stream>>>(Opart, Mpart, Lpart, Ob);
    out_proj_kernel<<<dim3(32, 8, BATCH), 256, 0, stream>>>(Ob, Wo, out);
}

// Round 3
// 224.946 us; speedup vs baseline: 1.6005x; 1.1175x over previous
//
#include <hip/hip_runtime.h>
#include <hip/hip_bf16.h>

#define S_LEN 4096
#define BATCH 4
#define DMODEL 1024
#define HDIM 128
#define NSLOT 4   // KV chunks per q-tile (equal split of the causal range)

typedef __attribute__((ext_vector_type(8))) short short8;
typedef __attribute__((ext_vector_type(4))) short short4v;
typedef __attribute__((ext_vector_type(4))) float float4v;

#define MASKVAL (-3.0e38f)
#define MINIT   (-1.0e30f)

static __device__ __forceinline__ unsigned short f2bf(float f) {
    __hip_bfloat16 h = __float2bfloat16(f);
    return *reinterpret_cast<unsigned short*>(&h);
}
static __device__ __forceinline__ unsigned short f2h(float f) {
    _Float16 h = (_Float16)f; return *reinterpret_cast<unsigned short*>(&h);
}
static __device__ __forceinline__ float h2f(unsigned short u) {
    _Float16 h = *reinterpret_cast<_Float16*>(&u); return (float)h;
}

// ---------------------------------------------------------------------------
// Kernel A: QKV projection, per-batch tiled.  For which=0/1 writes (B,S,H);
// for which=2 (V) swaps MFMA operands and writes V^T as (B,H,S).
// ---------------------------------------------------------------------------
__global__ __launch_bounds__(256) void qkv_proj_kernel(
    const float* __restrict__ x, const float* __restrict__ Wq,
    const float* __restrict__ Wk, const float* __restrict__ Wv,
    unsigned short* __restrict__ Qb, unsigned short* __restrict__ Kb,
    unsigned short* __restrict__ Vtb)
{
    __shared__ unsigned short As[128 * 72];
    __shared__ unsigned short Bs[128 * 72];

    const int t = threadIdx.x;
    const int s0 = blockIdx.x * 128;
    const int b = blockIdx.y;
    const int which = blockIdx.z;
    const float* W = (which == 0) ? Wq : (which == 1) ? Wk : Wv;

    const int lane = t & 63;
    const int w = t >> 6;
    const int wr = (w >> 1) * 64;
    const int wc = (w & 1) * 64;
    const int l15 = lane & 15;
    const int l4 = lane >> 4;

    float4v acc[4][4];
#pragma unroll
    for (int i = 0; i < 4; i++)
#pragma unroll
        for (int j = 0; j < 4; j++) acc[i][j] = (float4v){0.f, 0.f, 0.f, 0.f};

    const int krow = t >> 4;
    const int kcol4 = (t & 15) * 4;

    for (int k0 = 0; k0 < DMODEL; k0 += 64) {
        __syncthreads();
#pragma unroll
        for (int p = 0; p < 8; p++) {
            int row = p * 16 + krow;
            float4 v = *reinterpret_cast<const float4*>(
                &x[((size_t)(s0 + row) * BATCH + b) * DMODEL + k0 + kcol4]);
            short4v h;
            h[0] = (short)f2bf(v.x); h[1] = (short)f2bf(v.y);
            h[2] = (short)f2bf(v.z); h[3] = (short)f2bf(v.w);
            *reinterpret_cast<short4v*>(&As[row * 72 + kcol4]) = h;
        }
#pragma unroll
        for (int p = 0; p < 8; p++) {
            int row = p * 16 + krow;
            float4 v = *reinterpret_cast<const float4*>(
                &W[(size_t)row * DMODEL + k0 + kcol4]);
            short4v h;
            h[0] = (short)f2bf(v.x); h[1] = (short)f2bf(v.y);
            h[2] = (short)f2bf(v.z); h[3] = (short)f2bf(v.w);
            *reinterpret_cast<short4v*>(&Bs[row * 72 + kcol4]) = h;
        }
        __syncthreads();

#pragma unroll
        for (int kk = 0; kk < 64; kk += 32) {
            short8 a[4], bfr[4];
#pragma unroll
            for (int mi = 0; mi < 4; mi++)
                a[mi] = *reinterpret_cast<const short8*>(
                    &As[(wr + mi * 16 + l15) * 72 + kk + l4 * 8]);
#pragma unroll
            for (int ni = 0; ni < 4; ni++)
                bfr[ni] = *reinterpret_cast<const short8*>(
                    &Bs[(wc + ni * 16 + l15) * 72 + kk + l4 * 8]);
            if (which != 2) {
#pragma unroll
                for (int mi = 0; mi < 4; mi++)
#pragma unroll
                    for (int ni = 0; ni < 4; ni++)
                        acc[mi][ni] = __builtin_amdgcn_mfma_f32_16x16x32_bf16(
                            a[mi], bfr[ni], acc[mi][ni], 0, 0, 0);
            } else {
#pragma unroll
                for (int mi = 0; mi < 4; mi++)
#pragma unroll
                    for (int ni = 0; ni < 4; ni++)
                        acc[mi][ni] = __builtin_amdgcn_mfma_f32_16x16x32_bf16(
                            bfr[ni], a[mi], acc[mi][ni], 0, 0, 0);
            }
        }
    }

    if (which != 2) {
        unsigned short* Out = (which == 0) ? Qb : Kb;
        const float scale = (which == 0) ? 0.08838834764831845f : 1.0f;
#pragma unroll
        for (int mi = 0; mi < 4; mi++)
#pragma unroll
            for (int ni = 0; ni < 4; ni++)
#pragma unroll
                for (int r = 0; r < 4; r++) {
                    int s = s0 + wr + mi * 16 + l4 * 4 + r;
                    int h = wc + ni * 16 + l15;
                    Out[((size_t)b * S_LEN + s) * HDIM + h] =
                        f2bf(acc[mi][ni][r] * scale);
                }
    } else {
#pragma unroll
        for (int mi = 0; mi < 4; mi++)
#pragma unroll
            for (int ni = 0; ni < 4; ni++)
#pragma unroll
                for (int r = 0; r < 4; r++) {
                    int h = wc + ni * 16 + l4 * 4 + r;
                    int s = s0 + wr + mi * 16 + l15;
                    Vtb[((size_t)b * HDIM + h) * S_LEN + s] = f2bf(acc[mi][ni][r]);
                }
    }
}

// ---------------------------------------------------------------------------
// Kernel B: causal flash attention.  8 waves, 128 q rows per block.
// Each block: (qtile, batch, chunk c of NSLOT equal KV chunks).
// Writes normalized fp16 partial O + per-row (m, l).
// ---------------------------------------------------------------------------
__global__ __launch_bounds__(512) void attn_kernel(
    const unsigned short* __restrict__ Qb, const unsigned short* __restrict__ Kb,
    const unsigned short* __restrict__ Vtb, unsigned short* __restrict__ Opart,
    float* __restrict__ Mpart, float* __restrict__ Lpart)
{
    __shared__ unsigned short Ks[64 * 128];    // [kv][h], row-swizzled
    __shared__ unsigned short Vs[128 * 64];    // [h][kv], row-swizzled
    __shared__ unsigned short Pl[8 * 16 * 64]; // per-wave P

    const int t = threadIdx.x;
    const int w = t >> 6;
    const int lane = t & 63;
    const int l15 = lane & 15, l4 = lane >> 4;
    const int b = blockIdx.y;
    const int c = blockIdx.z;
    const int qt = 31 - blockIdx.x;           // big tiles first

    const int nkv = 2 * (qt + 1);             // kv-blocks in causal range
    const int csize = (nkv + NSLOT - 1) / NSLOT;
    const int lo = c * csize;
    const int hi = min(lo + csize, nkv);
    if (lo >= hi) return;                     // empty chunk: whole block exits

    const int qb = qt * 128;
    const size_t base = (size_t)b * S_LEN * HDIM;

    // Q fragments (16 rows per wave)
    short8 qf[4];
    {
        int qrow = qb + w * 16 + l15;
#pragma unroll
        for (int kk = 0; kk < 4; kk++)
            qf[kk] = *reinterpret_cast<const short8*>(
                &Qb[base + (size_t)qrow * HDIM + kk * 32 + l4 * 8]);
    }

    float m_run[4], l_run[4];
    float4v acc_o[8];
#pragma unroll
    for (int r = 0; r < 4; r++) { m_run[r] = MINIT; l_run[r] = 0.f; }
#pragma unroll
    for (int hf = 0; hf < 8; hf++) acc_o[hf] = (float4v){0.f, 0.f, 0.f, 0.f};

    // staging assignments (512 threads)
    const int kr = t >> 3, kc = (t & 7) * 16;   // K: 64 rows, 8 thr/row, 2x uint4
    const int vh = t >> 2, vc = (t & 3) * 16;   // V^T: 128 rows, 4 thr/row, 2x uint4
    uint4 kreg[2], vreg[2];
    {
        int kvb = lo * 64;
        const unsigned short* kp = &Kb[base + (size_t)(kvb + kr) * HDIM + kc];
#pragma unroll
        for (int j = 0; j < 2; j++)
            kreg[j] = *reinterpret_cast<const uint4*>(kp + j * 8);
        const unsigned short* vp = &Vtb[((size_t)b * HDIM + vh) * S_LEN + kvb + vc];
#pragma unroll
        for (int j = 0; j < 2; j++)
            vreg[j] = *reinterpret_cast<const uint4*>(vp + j * 8);
    }

    for (int ti = lo; ti < hi; ti++) {
        int kvb = ti * 64;
        __syncthreads();   // previous iteration's LDS reads done
#pragma unroll
        for (int j = 0; j < 2; j++) {
            int off = (kr * 256 + (kc + j * 8) * 2) ^ ((kr & 7) << 4);
            *reinterpret_cast<uint4*>(reinterpret_cast<char*>(Ks) + off) = kreg[j];
        }
#pragma unroll
        for (int j = 0; j < 2; j++) {
            int off = (vh * 128 + (vc + j * 8) * 2) ^ ((vh & 7) << 4);
            *reinterpret_cast<uint4*>(reinterpret_cast<char*>(Vs) + off) = vreg[j];
        }
        __syncthreads();
        if (ti + 1 < hi) {   // prefetch next tile into regs
            int kvb2 = (ti + 1) * 64;
            const unsigned short* kp = &Kb[base + (size_t)(kvb2 + kr) * HDIM + kc];
#pragma unroll
            for (int j = 0; j < 2; j++)
                kreg[j] = *reinterpret_cast<const uint4*>(kp + j * 8);
            const unsigned short* vp = &Vtb[((size_t)b * HDIM + vh) * S_LEN + kvb2 + vc];
#pragma unroll
            for (int j = 0; j < 2; j++)
                vreg[j] = *reinterpret_cast<const uint4*>(vp + j * 8);
        }

        // S = Q K^T
        float4v accs[4];
#pragma unroll
        for (int fi = 0; fi < 4; fi++) {
            accs[fi] = (float4v){0.f, 0.f, 0.f, 0.f};
#pragma unroll
            for (int kk = 0; kk < 4; kk++) {
                int krow = fi * 16 + l15;
                int off = (krow * 256 + (kk * 32 + l4 * 8) * 2) ^ ((krow & 7) << 4);
                short8 kf = *reinterpret_cast<const short8*>(
                    reinterpret_cast<const char*>(Ks) + off);
                accs[fi] = __builtin_amdgcn_mfma_f32_16x16x32_bf16(
                    qf[kk], kf, accs[fi], 0, 0, 0);
            }
        }
        // causal mask: kv-blocks at/above the diagonal band of this 128-row tile
        if (kvb + 63 > qb + w * 16) {
#pragma unroll
            for (int fi = 0; fi < 4; fi++)
#pragma unroll
                for (int r = 0; r < 4; r++) {
                    int q = qb + w * 16 + l4 * 4 + r;
                    int kv = kvb + fi * 16 + l15;
                    if (kv > q) accs[fi][r] = MASKVAL;
                }
        }
        // online softmax (rows live in 16-lane groups)
        float alpha[4];
#pragma unroll
        for (int r = 0; r < 4; r++) {
            float mx = fmaxf(fmaxf(accs[0][r], accs[1][r]),
                             fmaxf(accs[2][r], accs[3][r]));
#pragma unroll
            for (int d = 1; d < 16; d <<= 1) mx = fmaxf(mx, __shfl_xor(mx, d));
            float mnew = fmaxf(m_run[r], mx);   // >= MINIT always
            alpha[r] = __expf(m_run[r] - mnew);
            m_run[r] = mnew;
        }
        float p[4][4];
#pragma unroll
        for (int fi = 0; fi < 4; fi++)
#pragma unroll
            for (int r = 0; r < 4; r++)
                p[fi][r] = __expf(accs[fi][r] - m_run[r]);
#pragma unroll
        for (int r = 0; r < 4; r++) {
            float s = p[0][r] + p[1][r] + p[2][r] + p[3][r];
#pragma unroll
            for (int d = 1; d < 16; d <<= 1) s += __shfl_xor(s, d);
            l_run[r] = l_run[r] * alpha[r] + s;
#pragma unroll
            for (int hf = 0; hf < 8; hf++) acc_o[hf][r] *= alpha[r];
        }
        // P -> per-wave LDS
        char* pbase = reinterpret_cast<char*>(Pl) + w * 2048;
#pragma unroll
        for (int fi = 0; fi < 4; fi++)
#pragma unroll
            for (int r = 0; r < 4; r++) {
                int row = l4 * 4 + r;
                int kv = fi * 16 + l15;
                int off = (row * 128 + kv * 2) ^ ((row & 7) << 4);
                *reinterpret_cast<short*>(pbase + off) = (short)f2bf(p[fi][r]);
            }
        // O += P @ V
#pragma unroll
        for (int kk = 0; kk < 2; kk++) {
            int poff = (l15 * 128 + (kk * 32 + l4 * 8) * 2) ^ ((l15 & 7) << 4);
            short8 pa = *reinterpret_cast<const short8*>(pbase + poff);
#pragma unroll
            for (int hf = 0; hf < 8; hf++) {
                int h = hf * 16 + l15;
                int voff = (h * 128 + (kk * 32 + l4 * 8) * 2) ^ ((h & 7) << 4);
                short8 vf = *reinterpret_cast<const short8*>(
                    reinterpret_cast<const char*>(Vs) + voff);
                acc_o[hf] = __builtin_amdgcn_mfma_f32_16x16x32_bf16(
                    pa, vf, acc_o[hf], 0, 0, 0);
            }
        }
    }

    // epilogue: normalized fp16 partial + (m,l);  l==0 -> zeros (fully masked)
    const size_t R0 = (size_t)(c * BATCH + b) * S_LEN;
#pragma unroll
    for (int r = 0; r < 4; r++) {
        int q = qb + w * 16 + l4 * 4 + r;
        float inv = (l_run[r] > 0.f) ? 1.f / l_run[r] : 0.f;
#pragma unroll
        for (int hf = 0; hf < 8; hf++) {
            int h = hf * 16 + l15;
            Opart[(R0 + q) * HDIM + h] = f2h(acc_o[hf][r] * inv);
        }
        if (l15 == 0) { Mpart[R0 + q] = m_run[r]; Lpart[R0 + q] = l_run[r]; }
    }
}

// ---------------------------------------------------------------------------
// Kernel B2: combine partials -> Ob (B,S,H) bf16
// ---------------------------------------------------------------------------
__global__ __launch_bounds__(256) void combine_kernel(
    const unsigned short* __restrict__ Opart, const float* __restrict__ Mpart,
    const float* __restrict__ Lpart, unsigned short* __restrict__ Ob)
{
    const int BS = BATCH * S_LEN;
    int idx = blockIdx.x * 256 + threadIdx.x;
    int r = idx >> 4, hc = (idx & 15) * 8;
    int q = r & (S_LEN - 1);
    int qt = q >> 7;
    int nkv = 2 * (qt + 1);
    int csize = (nkv + NSLOT - 1) / NSLOT;
    int cnt = (nkv + csize - 1) / csize;     // # non-empty chunks

    float m = -INFINITY;
    for (int j = 0; j < cnt; j++) m = fmaxf(m, Mpart[j * BS + r]);
    float wsum = 0.f;
    float acc[8];
#pragma unroll
    for (int e = 0; e < 8; e++) acc[e] = 0.f;
    for (int j = 0; j < cnt; j++) {
        float wj = __expf(Mpart[j * BS + r] - m) * Lpart[j * BS + r];
        wsum += wj;
        short8 o = *reinterpret_cast<const short8*>(
            &Opart[((size_t)j * BS + r) * HDIM + hc]);
#pragma unroll
        for (int e = 0; e < 8; e++) acc[e] += wj * h2f((unsigned short)o[e]);
    }
    float inv = 1.f / wsum;
    short8 ob;
#pragma unroll
    for (int e = 0; e < 8; e++) ob[e] = (short)f2bf(acc[e] * inv);
    *reinterpret_cast<short8*>(&Ob[(size_t)r * HDIM + hc]) = ob;
}

// ---------------------------------------------------------------------------
// Kernel C: output projection, per-batch tiled.
// ---------------------------------------------------------------------------
__global__ __launch_bounds__(256) void out_proj_kernel(
    const unsigned short* __restrict__ Ob, const float* __restrict__ Wo,
    float* __restrict__ out)
{
    __shared__ unsigned short As[128 * 128];
    __shared__ unsigned short Bs[128 * 128];

    const int t = threadIdx.x;
    const int lane = t & 63, w = t >> 6;
    const int l15 = lane & 15, l4 = lane >> 4;
    const int wr = (w >> 1) * 64, wc = (w & 1) * 64;
    const int s0 = blockIdx.x * 128;
    const int d0 = blockIdx.y * 128;
    const int b = blockIdx.z;

#pragma unroll
    for (int p = 0; p < 8; p++) {
        int e = p * 2048 + t * 8;
        int r = e >> 7, h = e & 127;
        short8 v = *reinterpret_cast<const short8*>(
            &Ob[((size_t)b * S_LEN + s0 + r) * HDIM + h]);
        int off = (r * 256 + h * 2) ^ ((r & 7) << 4);
        *reinterpret_cast<short8*>(reinterpret_cast<char*>(As) + off) = v;
    }
#pragma unroll
    for (int p = 0; p < 16; p++) {
        int e = p * 1024 + t * 4;
        int r = e >> 7, h = e & 127;
        float4 v = *reinterpret_cast<const float4*>(&Wo[(size_t)(d0 + r) * HDIM + h]);
        short4v hh;
        hh[0] = (short)f2bf(v.x); hh[1] = (short)f2bf(v.y);
        hh[2] = (short)f2bf(v.z); hh[3] = (short)f2bf(v.w);
        int off = (r * 256 + h * 2) ^ ((r & 7) << 4);
        *reinterpret_cast<short4v*>(reinterpret_cast<char*>(Bs) + off) = hh;
    }
    __syncthreads();

    float4v acc[4][4];
#pragma unroll
    for (int i = 0; i < 4; i++)
#pragma unroll
        for (int j = 0; j < 4; j++) acc[i][j] = (float4v){0.f, 0.f, 0.f, 0.f};

#pragma unroll
    for (int kk = 0; kk < 4; kk++) {
        short8 a[4], bf[4];
#pragma unroll
        for (int mi = 0; mi < 4; mi++) {
            int row = wr + mi * 16 + l15;
            int off = (row * 256 + (kk * 32 + l4 * 8) * 2) ^ ((row & 7) << 4);
            a[mi] = *reinterpret_cast<const short8*>(
                reinterpret_cast<const char*>(As) + off);
        }
#pragma unroll
        for (int ni = 0; ni < 4; ni++) {
            int row = wc + ni * 16 + l15;
            int off = (row * 256 + (kk * 32 + l4 * 8) * 2) ^ ((row & 7) << 4);
            bf[ni] = *reinterpret_cast<const short8*>(
                reinterpret_cast<const char*>(Bs) + off);
        }
#pragma unroll
        for (int mi = 0; mi < 4; mi++)
#pragma unroll
            for (int ni = 0; ni < 4; ni++)
                acc[mi][ni] = __builtin_amdgcn_mfma_f32_16x16x32_bf16(
                    a[mi], bf[ni], acc[mi][ni], 0, 0, 0);
    }

#pragma unroll
    for (int mi = 0; mi < 4; mi++)
#pragma unroll
        for (int ni = 0; ni < 4; ni++)
#pragma unroll
            for (int r = 0; r < 4; r++) {
                int s = s0 + wr + mi * 16 + l4 * 4 + r;
                int d = d0 + wc + ni * 16 + l15;
                out[((size_t)s * BATCH + b) * DMODEL + d] = acc[mi][ni][r];
            }
}

// ---------------------------------------------------------------------------
extern "C" void kernel_launch(void* const* d_in, const int* in_sizes, int n_in,
                              void* d_out, int out_size, void* d_ws, size_t ws_size,
                              hipStream_t stream) {
    const float* x  = (const float*)d_in[0];
    const float* Wq = (const float*)d_in[1];
    const float* Wk = (const float*)d_in[2];
    const float* Wv = (const float*)d_in[3];
    const float* Wo = (const float*)d_in[4];
    float* out = (float*)d_out;

    const size_t elems = (size_t)BATCH * S_LEN * HDIM;     // 2M
    const size_t BS = (size_t)BATCH * S_LEN;               // 16384
    unsigned short* Qb    = (unsigned short*)d_ws;
    unsigned short* Kb    = Qb + elems;
    unsigned short* Vtb   = Kb + elems;
    unsigned short* Ob    = Vtb + elems;
    unsigned short* Opart = Ob + elems;                    // NSLOT*BS*H fp16
    float* Mpart = (float*)(Opart + (size_t)NSLOT * BS * HDIM);
    float* Lpart = Mpart + (size_t)NSLOT * BS;

    qkv_proj_kernel<<<dim3(32, BATCH, 3), 256, 0, stream>>>(x, Wq, Wk, Wv, Qb, Kb, Vtb);
    attn_kernel<<<dim3(32, BATCH, NSLOT), 512, 0, stream>>>(Qb, Kb, Vtb, Opart, Mpart, Lpart);
    combine_kernel<<<dim3(1024), 256, 0, stream>>>(Opart, Mpart, Lpart, Ob);
    out_proj_kernel<<<dim3(32, 8, BATCH), 256, 0, stream>>>(Ob, Wo, out);
}